// Round 1
// baseline (58.578 us; speedup 1.0000x reference)
//
#include <hip/hip_runtime.h>
#include <math.h>

#define BINS 10
#define NCLS 1000
#define NC4  250   // 1000 floats = 250 float4 per row
#define EPSV 1e-8f

// Pass 1: one 64-lane wave per row. Each lane loads up to 4 float4 (coalesced,
// row stride 4000 B is 16B-aligned). Butterfly-reduce max, then sum(exp(x-m)).
// Lane 0 computes loss_i and bin_i, accumulates into LDS per-bin (count, loss
// sum). Block flushes <=10 global atomics at the end.
__global__ __launch_bounds__(256) void ghmc_pass1(
    const float* __restrict__ pred,
    const int*   __restrict__ target,
    int*   __restrict__ gcnt,
    float* __restrict__ gsum,
    int rows_per_block, int nrows)
{
    __shared__ int   s_cnt[BINS];
    __shared__ float s_sum[BINS];
    if (threadIdx.x < BINS) { s_cnt[threadIdx.x] = 0; s_sum[threadIdx.x] = 0.0f; }
    __syncthreads();

    const int lane = threadIdx.x & 63;
    const int wave = threadIdx.x >> 6;
    const int base = blockIdx.x * rows_per_block;

    for (int r = wave; r < rows_per_block; r += 4) {
        const int row = base + r;
        if (row >= nrows) break;
        const float4* rp = (const float4*)(pred + (size_t)row * NCLS);

        // 250 float4: chunks at lane, lane+64, lane+128 always valid
        // (max idx 191 < 250); chunk 3 valid only for lane < 58.
        float4 v0 = rp[lane];
        float4 v1 = rp[lane + 64];
        float4 v2 = rp[lane + 128];
        float4 v3;
        if (lane + 192 < NC4) {
            v3 = rp[lane + 192];
        } else {
            v3.x = -INFINITY; v3.y = -INFINITY; v3.z = -INFINITY; v3.w = -INFINITY;
        }

        float m = fmaxf(fmaxf(fmaxf(v0.x, v0.y), fmaxf(v0.z, v0.w)),
                        fmaxf(fmaxf(v1.x, v1.y), fmaxf(v1.z, v1.w)));
        m = fmaxf(m, fmaxf(fmaxf(v2.x, v2.y), fmaxf(v2.z, v2.w)));
        m = fmaxf(m, fmaxf(fmaxf(v3.x, v3.y), fmaxf(v3.z, v3.w)));
        #pragma unroll
        for (int off = 32; off >= 1; off >>= 1)
            m = fmaxf(m, __shfl_xor(m, off));

        // exp(-inf - m) = 0, so masked chunk-3 lanes contribute nothing.
        float s = __expf(v0.x - m) + __expf(v0.y - m) + __expf(v0.z - m) + __expf(v0.w - m)
                + __expf(v1.x - m) + __expf(v1.y - m) + __expf(v1.z - m) + __expf(v1.w - m)
                + __expf(v2.x - m) + __expf(v2.y - m) + __expf(v2.z - m) + __expf(v2.w - m)
                + __expf(v3.x - m) + __expf(v3.y - m) + __expf(v3.z - m) + __expf(v3.w - m);
        #pragma unroll
        for (int off = 32; off >= 1; off >>= 1)
            s += __shfl_xor(s, off);

        if (lane == 0) {
            const int t = target[row];
            const float pt  = pred[(size_t)row * NCLS + t];  // L1-hot: wave just read this row
            const float lse = m + __logf(s);                 // log(sum(exp(pred)))
            // loss = -pred[t] + log(sum(exp(pred)) + eps)
            const float loss = -pt + lse + log1pf(EPSV * __expf(-lse));
            const float p = __expf(pt - lse);                // softmax[i, t]
            const float g = 1.0f - p;
            int b = (int)floorf(g * 10.0f);
            b = min(max(b, 0), BINS - 1);
            atomicAdd(&s_cnt[b], 1);
            atomicAdd(&s_sum[b], loss);
        }
    }

    __syncthreads();
    if (threadIdx.x < BINS && s_cnt[threadIdx.x] > 0) {
        atomicAdd(&gcnt[threadIdx.x], s_cnt[threadIdx.x]);
        atomicAdd(&gsum[threadIdx.x], s_sum[threadIdx.x]);
    }
}

// Pass 2: combine the 10 bins.
// out = sum_b (loss_sum[b] / counts[b]) / n_nonempty
__global__ void ghmc_pass2(const int* __restrict__ gcnt,
                           const float* __restrict__ gsum,
                           float* __restrict__ out)
{
    if (threadIdx.x == 0 && blockIdx.x == 0) {
        int n = 0;
        float acc = 0.0f;
        for (int b = 0; b < BINS; ++b) {
            if (gcnt[b] > 0) {
                n += 1;
                acc += gsum[b] / (float)gcnt[b];
            }
        }
        out[0] = acc / (float)max(n, 1);
    }
}

extern "C" void kernel_launch(void* const* d_in, const int* in_sizes, int n_in,
                              void* d_out, int out_size, void* d_ws, size_t ws_size,
                              hipStream_t stream)
{
    const float* pred   = (const float*)d_in[0];
    const int*   target = (const int*)d_in[1];
    const int nrows = in_sizes[1];          // 65536

    int*   gcnt = (int*)d_ws;
    float* gsum = (float*)((char*)d_ws + 64);

    // ws is poisoned 0xAA and not re-poisoned between replays: zero it every call.
    hipMemsetAsync(d_ws, 0, 128, stream);

    const int rows_per_block = 64;          // 1024 blocks, 4 waves each
    const int blocks = (nrows + rows_per_block - 1) / rows_per_block;
    ghmc_pass1<<<blocks, 256, 0, stream>>>(pred, target, gcnt, gsum,
                                           rows_per_block, nrows);
    ghmc_pass2<<<1, 64, 0, stream>>>(gcnt, gsum, (float*)d_out);
}